// Round 5
// baseline (375.205 us; speedup 1.0000x reference)
//
#include <hip/hip_runtime.h>
#include <stdint.h>

#define BATCH 16
#define NROW 25200
#define NCLS 80
#define ROWF 85
#define MAXDET 300
#define MAXNMS 30000u
#define NBIN 3072
#define BASEBITS 0x3EC00000u
#define CAP 32768u
#define BATCH_FLOATS 2142000   // 25200*85

#define PREBIN 2048            // score >= 0.75
#define NBUCK 1024             // NBIN - PREBIN
#define CANDCAP 131072u        // dense per-batch candidate cap (~69k expected)
#define KMAX 2048u             // per-block LDS staging cap (~700 expected)

#define GATHER_MIN 512u
#define SORTCAP 1024
#define CH_SZ 128

// fallback-hist tiling (R3-proven structure)
#define TILE_ROWS 80
#define TILE_FLOATS 6800
#define RPB 400
#define SUBT 5
#define SBLK 63

// staging grid
#define ROWS_PER_BLK 256
#define SBLK2 99               // ceil(25200/256)

// exact: fl(inter/den) > 0.5, division only at the rounding boundary
__device__ __forceinline__ bool iou_gt_half(float ax1, float ay1, float ax2, float ay2, float aa,
                                            float bx1, float by1, float bx2, float by2, float ba) {
    float ltx = fmaxf(ax1, bx1), lty = fmaxf(ay1, by1);
    float rbx = fminf(ax2, bx2), rby = fminf(ay2, by2);
    float wx = fmaxf(__fsub_rn(rbx, ltx), 0.0f);
    float wy = fmaxf(__fsub_rn(rby, lty), 0.0f);
    float inter = __fmul_rn(wx, wy);
    float den = __fadd_rn(__fsub_rn(__fadd_rn(aa, ba), inter), 1e-9f);
    float t = __fmul_rn(0.5f, den);            // exact (pow2 scale)
    if (!(inter > t)) return false;            // r <= 0.5  ->  fl(r) <= 0.5
    float tg = __fmul_rn(0.50000012f, den);    // safely above the tie zone
    if (inter >= tg) return true;
    return __fdiv_rn(inter, den) > 0.5f;       // boundary: exact division
}

__device__ __forceinline__ unsigned bin_of_bits(unsigned bits) {
    unsigned v = (bits - BASEBITS) >> 12;
    if (v > (unsigned)(NBIN - 1)) v = NBIN - 1;
    return v;
}

// ---------------- K1: LDS-staged threshold filter -> dense per-batch array -----------
__global__ __launch_bounds__(256) void k_stage(const float* __restrict__ pred,
                                               unsigned* __restrict__ ghist,
                                               unsigned* __restrict__ ccnt,
                                               unsigned long long* __restrict__ cand,
                                               unsigned* __restrict__ oflow,
                                               int staged) {
    if (!staged) return;
    __shared__ unsigned shist[NBUCK];            // 4 KB
    __shared__ unsigned long long skey[KMAX];    // 16 KB
    __shared__ unsigned s_cnt, s_n, s_base;
    int bx = blockIdx.x;
    int b = bx / SBLK2, blk = bx - b * SBLK2;
    int t = threadIdx.x, lane = t & 63, wv = t >> 6;
    for (int i = t; i < NBUCK; i += 256) shist[i] = 0u;
    if (t == 0) s_cnt = 0u;
    __syncthreads();
    const float* pb = pred + (size_t)b * BATCH_FLOATS;
    int r0 = blk * ROWS_PER_BLK + wv * 64;
    int rown = NROW - r0;
    if (rown > 0) {
        if (rown > 64) rown = 64;
        float obj = 0.0f;
        if (lane < rown) obj = pb[(size_t)(r0 + lane) * ROWF + 4];
        unsigned long long live = __ballot(obj > 0.4f);
        while (live) {
            int j = (int)__builtin_ctzll(live);
            live &= live - 1ULL;
            float o = __shfl(obj, j);
            const float* rp = pb + (size_t)(r0 + j) * ROWF;
            unsigned grow = (unsigned)(r0 + j);
            // classes 0..63
            {
                float s = __fmul_rn(rp[5 + lane], o);   // exact numpy op order
                if (s >= 0.75f) {
                    unsigned bits = __float_as_uint(s);
                    unsigned bin = bin_of_bits(bits);
                    atomicAdd(&shist[bin - PREBIN], 1u);
                    unsigned u = atomicAdd(&s_cnt, 1u);
                    unsigned flat = grow * (unsigned)NCLS + (unsigned)lane;
                    if (u < KMAX)
                        skey[u] = ((unsigned long long)bits << 32) |
                                  (unsigned long long)(0xFFFFFFFFu - flat);
                    else oflow[b] = 1u;
                }
            }
            // classes 64..79
            if (lane < 16) {
                int c = 64 + lane;
                float s = __fmul_rn(rp[5 + c], o);
                if (s >= 0.75f) {
                    unsigned bits = __float_as_uint(s);
                    unsigned bin = bin_of_bits(bits);
                    atomicAdd(&shist[bin - PREBIN], 1u);
                    unsigned u = atomicAdd(&s_cnt, 1u);
                    unsigned flat = grow * (unsigned)NCLS + (unsigned)c;
                    if (u < KMAX)
                        skey[u] = ((unsigned long long)bits << 32) |
                                  (unsigned long long)(0xFFFFFFFFu - flat);
                    else oflow[b] = 1u;
                }
            }
        }
    }
    __syncthreads();
    // per-block histogram, coalesced (no global atomics)
    unsigned* gh = ghist + (size_t)(b * SBLK2 + blk) * NBUCK;
    for (int i = t; i < NBUCK; i += 256) gh[i] = shist[i];
    if (t == 0) {
        unsigned n = s_cnt;
        if (n > KMAX) n = KMAX;                 // oflow already flagged
        unsigned base = atomicAdd(&ccnt[b], n); // ONE returning atomic per block
        if (base + n > CANDCAP) oflow[b] = 1u;
        s_n = n; s_base = base;
    }
    __syncthreads();
    unsigned n = s_n, base = s_base;
    if (base + n <= CANDCAP) {
        unsigned long long* cd = cand + (size_t)b * CANDCAP + base;
        for (unsigned k = t; k < n; k += 256) cd[k] = skey[k];   // coalesced dense
    }
}

// ---------------- K2: reduce per-block hists -> suffix scan -> meta ------------------
__global__ __launch_bounds__(256) void k_prep(const unsigned* __restrict__ ghist,
                                              const unsigned* __restrict__ ccnt,
                                              const unsigned* __restrict__ oflow,
                                              unsigned* __restrict__ suf2,
                                              int* __restrict__ meta,
                                              int staged) {
    __shared__ unsigned sh[NBUCK];
    __shared__ unsigned sS[NBUCK];
    __shared__ unsigned cs[256];
    __shared__ int s_cut, s_need, s_tot;
    __shared__ unsigned s_bad;
    int b = blockIdx.x, t = threadIdx.x;
    // reduce 99 block-hists
    for (int i = t; i < NBUCK; i += 256) {
        unsigned s = 0;
        const unsigned* g = ghist + (size_t)b * SBLK2 * NBUCK + i;
        for (int k = 0; k < SBLK2; ++k) s += g[(size_t)k * NBUCK];
        sh[i] = s;
    }
    if (t == 0) { s_cut = -1; s_need = 0; s_tot = 0; s_bad = 0u; }
    __syncthreads();
    for (int i = t; i < NBUCK; i += 256)
        if (sh[i] > (unsigned)SORTCAP) atomicOr(&s_bad, 1u);   // fat bin -> fallback
    const int CHUNK = NBUCK / 256;  // 4
    int base = t * CHUNK;
    unsigned tot = 0;
    for (int i = 0; i < CHUNK; ++i) tot += sh[base + i];
    cs[t] = tot;
    __syncthreads();
    for (int off = 1; off < 256; off <<= 1) {
        unsigned v = (t + off < 256) ? cs[t + off] : 0u;
        __syncthreads();
        cs[t] += v;
        __syncthreads();
    }
    unsigned after = (t + 1 < 256) ? cs[t + 1] : 0u;
    for (int i = CHUNK - 1; i >= 0; --i) {
        after += sh[base + i];
        sS[base + i] = after;
    }
    __syncthreads();
    unsigned* g2 = suf2 + (size_t)b * (NBUCK + 1);
    for (int i = t; i < NBUCK; i += 256) g2[i] = sS[i];
    if (t == 0) g2[NBUCK] = 0u;
    for (int i = 0; i < CHUNK; ++i) {
        int v = base + i;
        unsigned Sv = sS[v];
        unsigned Sn = (v + 1 < NBUCK) ? sS[v + 1] : 0u;
        if (Sv >= MAXNMS && Sn < MAXNMS) {
            s_cut = PREBIN + v;
            s_need = (int)(MAXNMS - Sn);
            s_tot = (int)Sv;
        }
    }
    __syncthreads();
    if (t == 0) {
        int valid = (staged && s_cut >= 0 && s_bad == 0u &&
                     oflow[b] == 0u && ccnt[b] <= CANDCAP) ? 1 : 0;
        meta[b * 4 + 0] = valid ? s_cut : 0;
        meta[b * 4 + 1] = valid ? s_need : 0;
        meta[b * 4 + 2] = valid ? s_tot : 0;
        meta[b * 4 + 3] = valid;
    }
}

// ---------------- K3a (fallback): full histogram ------------------------------------
__global__ __launch_bounds__(256) void k_hist_fb(const float* __restrict__ pred,
                                                 unsigned* __restrict__ hist,
                                                 const int* __restrict__ meta) {
    int bx = blockIdx.x;
    int b = bx / SBLK, blk = bx - b * SBLK;
    if (meta[b * 4 + 3]) return;
    __shared__ __align__(16) float rows[TILE_FLOATS];
    __shared__ unsigned shist[NBIN];
    int t = threadIdx.x, lane = t & 63, wv = t >> 6;
    for (int i = t; i < NBIN; i += 256) shist[i] = 0u;
    const float* pbase = pred + (size_t)b * BATCH_FLOATS + (size_t)blk * RPB * ROWF;
    for (int st = 0; st < SUBT; ++st) {
        __syncthreads();
        const float4* src = (const float4*)(pbase + (size_t)st * TILE_ROWS * ROWF);
        float4* dst = (float4*)rows;
        for (int i = t; i < TILE_FLOATS / 4; i += 256) dst[i] = src[i];
        __syncthreads();
        for (int r = wv; r < TILE_ROWS; r += 4) {
            float obj = rows[r * ROWF + 4];
            if (!(obj > 0.4f)) continue;
            for (int half = 0; half < 2; ++half) {
                int c = lane + (half << 6);
                if (c < NCLS) {
                    float cv = rows[r * ROWF + 5 + c];
                    float s = __fmul_rn(cv, obj);
                    if (s > 0.4f) atomicAdd(&shist[bin_of_bits(__float_as_uint(s))], 1u);
                }
            }
        }
    }
    __syncthreads();
    unsigned* gh = hist + (size_t)b * NBIN;
    for (int i = t; i < NBIN; i += 256) {
        unsigned v = shist[i];
        if (v) atomicAdd(&gh[i], v);
    }
}

// ---------------- K3b (fallback): suffix-scan full hist -> meta + suf ----------------
__global__ __launch_bounds__(256) void k_scan_fb(const unsigned* __restrict__ hist,
                                                 unsigned* __restrict__ suf,
                                                 int* __restrict__ meta) {
    int b = blockIdx.x, t = threadIdx.x;
    if (meta[b * 4 + 3]) return;
    __shared__ unsigned sh[NBIN];
    __shared__ unsigned sS[NBIN];
    __shared__ unsigned cs[256];
    __shared__ int s_cut, s_need, s_tot;
    const unsigned* gh = hist + (size_t)b * NBIN;
    for (int i = t; i < NBIN; i += 256) sh[i] = gh[i];
    if (t == 0) { s_cut = 0; s_need = 0x7FFFFFFF; s_tot = 0; }
    __syncthreads();
    const int CHUNK = NBIN / 256;  // 12
    int base = t * CHUNK;
    unsigned tot = 0;
    for (int i = 0; i < CHUNK; ++i) tot += sh[base + i];
    cs[t] = tot;
    __syncthreads();
    for (int off = 1; off < 256; off <<= 1) {
        unsigned v = (t + off < 256) ? cs[t + off] : 0u;
        __syncthreads();
        cs[t] += v;
        __syncthreads();
    }
    unsigned after = (t + 1 < 256) ? cs[t + 1] : 0u;
    for (int i = CHUNK - 1; i >= 0; --i) {
        after += sh[base + i];
        sS[base + i] = after;
    }
    __syncthreads();
    unsigned* gs = suf + (size_t)b * (NBIN + 1);
    for (int i = t; i < NBIN; i += 256) gs[i] = sS[i];
    if (t == 0) gs[NBIN] = 0u;
    for (int i = 0; i < CHUNK; ++i) {
        int v = base + i;
        unsigned Sv = sS[v];
        unsigned Sn = (v + 1 < NBIN) ? sS[v + 1] : 0u;
        if (Sv >= MAXNMS && Sn < MAXNMS) {
            s_cut = v;
            s_need = (int)(MAXNMS - Sn);
            s_tot = (int)Sv;
        }
    }
    __syncthreads();
    if (t == 0) {
        int cut = s_cut, needv = s_need, totv = s_tot;
        if (sS[0] < MAXNMS) { cut = 0; needv = 0x7FFFFFFF; totv = (int)sS[0]; }
        meta[b * 4 + 0] = cut;
        meta[b * 4 + 1] = needv;
        meta[b * 4 + 2] = totv;
    }
}

// ---------------- K3c (fallback): full re-read counting-scatter ----------------------
__global__ __launch_bounds__(256) void k_scatter_fb(const float* __restrict__ pred,
                                                    const unsigned* __restrict__ suf,
                                                    const int* __restrict__ meta,
                                                    unsigned* __restrict__ cursor,
                                                    unsigned long long* __restrict__ keys) {
    int bx = blockIdx.x;
    int b = bx / SBLK, blk = bx - b * SBLK;
    if (meta[b * 4 + 3]) return;
    __shared__ __align__(16) float rows[TILE_FLOATS];
    int t = threadIdx.x, lane = t & 63, wv = t >> 6;
    int cutbin = meta[b * 4 + 0];
    const float* pbase = pred + (size_t)b * BATCH_FLOATS + (size_t)blk * RPB * ROWF;
    unsigned rowbase0 = (unsigned)(blk * RPB);
    const unsigned* gs = suf + (size_t)b * (NBIN + 1);
    unsigned* cur = cursor + (size_t)b * NBIN;
    unsigned long long* kb = keys + (size_t)b * CAP;
    for (int st = 0; st < SUBT; ++st) {
        __syncthreads();
        const float4* src = (const float4*)(pbase + (size_t)st * TILE_ROWS * ROWF);
        float4* dst = (float4*)rows;
        for (int i = t; i < TILE_FLOATS / 4; i += 256) dst[i] = src[i];
        __syncthreads();
        for (int r = wv; r < TILE_ROWS; r += 4) {
            float obj = rows[r * ROWF + 4];
            if (!(obj > 0.4f)) continue;
            unsigned grow = rowbase0 + (unsigned)(st * TILE_ROWS + r);
            for (int half = 0; half < 2; ++half) {
                int c = lane + (half << 6);
                if (c < NCLS) {
                    float cv = rows[r * ROWF + 5 + c];
                    float s = __fmul_rn(cv, obj);
                    if (s > 0.4f) {
                        unsigned bits = __float_as_uint(s);
                        unsigned bin = bin_of_bits(bits);
                        if ((int)bin >= cutbin) {
                            unsigned pos = gs[bin + 1] + atomicAdd(&cur[bin], 1u);
                            if (pos < CAP) {
                                unsigned flat = grow * (unsigned)NCLS + (unsigned)c;
                                kb[pos] = ((unsigned long long)bits << 32) |
                                          (unsigned long long)(0xFFFFFFFFu - flat);
                            }
                        }
                    }
                }
            }
        }
    }
}

// ---------------- K4: NMS — filter-scan gather, rank-place, 128-chunk mask -----------
__global__ __launch_bounds__(1024) void k_nms(const float* __restrict__ pred,
                                              const unsigned* __restrict__ suf,
                                              const unsigned* __restrict__ suf2,
                                              const int* __restrict__ meta,
                                              const unsigned* __restrict__ ccnt,
                                              const unsigned long long* __restrict__ keys,
                                              const unsigned long long* __restrict__ cand,
                                              float* __restrict__ out) {
    __shared__ unsigned sgsL[NBUCK + 1];                  // 4.1 KB
    __shared__ unsigned long long ktmp[SORTCAP];          // 8 KB
    __shared__ unsigned long long skeys[SORTCAP];         // 8 KB
    __shared__ unsigned maskW[CH_SZ][5];                  // 2.5 KB
    __shared__ unsigned sup0w[4];
    __shared__ float cbox[CH_SZ][9];                      // 4.6 KB
    __shared__ float kept[MAXDET][5];                     // 6 KB
    __shared__ int klist[MAXDET];
    __shared__ int s_nk, s_localk;
    __shared__ unsigned s_gc;

    int b = blockIdx.x;
    int tid = threadIdx.x;
    int lane = tid & 63, wv = tid >> 6;

    int cutbin = meta[b * 4 + 0];
    int needv  = meta[b * 4 + 1];
    unsigned total = (unsigned)meta[b * 4 + 2];
    int valid  = meta[b * 4 + 3];
    if (!valid && total > CAP) total = CAP;
    const unsigned* gs = suf + (size_t)b * (NBIN + 1);
    const unsigned* g2 = suf2 + (size_t)b * (NBUCK + 1);
    const unsigned long long* kb = keys + (size_t)b * CAP;
    const unsigned long long* cd = cand + (size_t)b * CANDCAP;
    unsigned ccb = valid ? ccnt[b] : 0u;
    if (ccb > CANDCAP) ccb = CANDCAP;
    const float* pb = pred + (size_t)b * BATCH_FLOATS;
    float* ob = out + (size_t)b * MAXDET * 6;

    if (valid) for (int i = tid; i < NBUCK + 1; i += 1024) sgsL[i] = g2[i];
    if (tid == 0) s_nk = 0;
    __syncthreads();

#define GSV(v) (valid ? sgsL[(v) - PREBIN] : gs[(v)])

    unsigned limit;
    if (needv == 0x7FFFFFFF) limit = total;
    else limit = GSV(cutbin + 1) + (unsigned)needv;
    if (limit > total) limit = total;

    unsigned p = 0;
    while (p < limit) {
        if (s_nk >= MAXDET) break;

        // ---- gather extent: whole bins, >= GATHER_MIN keys, <= SORTCAP ----
        int lo = cutbin, hi = NBIN - 1, w1 = cutbin;
        while (lo <= hi) { int mid = (lo + hi) >> 1;
            if (GSV(mid) > p) { w1 = mid; lo = mid + 1; } else hi = mid - 1; }
        lo = cutbin; hi = NBIN - 1; int w2 = cutbin;
        while (lo <= hi) { int mid = (lo + hi) >> 1;
            if (GSV(mid) >= p + GATHER_MIN) { w2 = mid; lo = mid + 1; } else hi = mid - 1; }
        unsigned gEnd = GSV(w2);
        if (gEnd <= p) gEnd = GSV(cutbin);
        if (gEnd - p > (unsigned)SORTCAP) {
            if (w2 < w1) gEnd = GSV(w2 + 1);
            if (gEnd - p > (unsigned)SORTCAP) gEnd = p + SORTCAP;  // unreachable when valid
        }
        unsigned G = gEnd - p;

        if (valid) {
            // ---- filter-scan dense array for bins [w2, w1] (exactly G keys) ----
            if (tid == 0) s_gc = 0u;
            __syncthreads();
            for (unsigned k = tid; k < ccb; k += 1024) {
                unsigned long long key = cd[k];
                unsigned v = bin_of_bits((unsigned)(key >> 32));
                if ((int)v >= w2 && (int)v <= w1) {
                    unsigned u = atomicAdd(&s_gc, 1u);
                    if (u < (unsigned)SORTCAP) ktmp[u] = key;
                }
            }
            __syncthreads();
            unsigned Gc = s_gc; if (Gc > (unsigned)SORTCAP) Gc = (unsigned)SORTCAP;
            // ---- rank-place into exact global order: (bin desc, key desc) ----
            if (tid < (int)Gc) {
                unsigned long long key = ktmp[tid];
                unsigned v = bin_of_bits((unsigned)(key >> 32));
                unsigned bstart = GSV(v + 1);
                unsigned rank = 0;
                for (unsigned u = 0; u < Gc; ++u) {
                    unsigned long long kk = ktmp[u];
                    unsigned vu = bin_of_bits((unsigned)(kk >> 32));
                    rank += (vu == v && kk > key) ? 1u : 0u;
                }
                skeys[(bstart - p) + rank] = key;
            }
            __syncthreads();
        } else {
            // ---- fallback: kb is bin-partitioned; rank-place within bins ----
            unsigned myLo = 0, myHi = 0;
            unsigned long long raw = 0ULL;
            if (tid < (int)G) {
                unsigned idx = p + (unsigned)tid;
                int l2 = cutbin, h2 = NBIN - 1, v = cutbin;
                while (l2 <= h2) { int mid = (l2 + h2) >> 1;
                    if (GSV(mid) > idx) { v = mid; l2 = mid + 1; } else h2 = mid - 1; }
                unsigned bstart = GSV(v + 1);
                unsigned bend = GSV(v);
                raw = kb[idx];
                myLo = bstart - p;
                myHi = bend - p; if (myHi > G) myHi = G;
                ktmp[tid] = raw;
            }
            __syncthreads();
            if (tid < (int)G) {
                unsigned rank = 0;
                for (unsigned u = myLo; u < myHi; ++u) rank += (ktmp[u] > raw) ? 1u : 0u;
                skeys[myLo + rank] = raw;
            }
            __syncthreads();
        }

        unsigned consumable = limit - p; if (consumable > G) consumable = G;

        // ---- process in chunks of 128 ----
        for (unsigned c0 = 0; c0 < consumable; c0 += CH_SZ) {
            int nk0 = s_nk;
            if (nk0 >= MAXDET) break;
            int CH = (int)((consumable - c0 < (unsigned)CH_SZ) ? (consumable - c0) : (unsigned)CH_SZ);

            if (tid < CH_SZ * 5) maskW[tid / 5][tid % 5] = 0u;
            if (tid >= CH_SZ * 5 && tid < CH_SZ * 5 + 4) sup0w[tid - CH_SZ * 5] = 0u;
            if (tid < CH) {
                unsigned long long kk = skeys[c0 + tid];
                unsigned flat = 0xFFFFFFFFu - (unsigned)kk;
                unsigned bi = flat / (unsigned)NCLS;
                unsigned cc = flat - bi * (unsigned)NCLS;
                const float* rp = pb + (size_t)bi * ROWF;
                float cx = rp[0], cy = rp[1], wd = rp[2], ht = rp[3];
                float hw = __fmul_rn(0.5f, wd), hh = __fmul_rn(0.5f, ht);
                float off = __fmul_rn((float)cc, 4096.0f);
                float x1 = __fsub_rn(cx, hw), y1 = __fsub_rn(cy, hh);
                float x2 = __fadd_rn(cx, hw), y2 = __fadd_rn(cy, hh);
                float ox1 = __fadd_rn(x1, off), oy1 = __fadd_rn(y1, off);
                float ox2 = __fadd_rn(x2, off), oy2 = __fadd_rn(y2, off);
                cbox[tid][0] = ox1; cbox[tid][1] = oy1;
                cbox[tid][2] = ox2; cbox[tid][3] = oy2;
                cbox[tid][4] = __fmul_rn(__fsub_rn(ox2, ox1), __fsub_rn(oy2, oy1));
            }
            __syncthreads();

            // split triangle mask + kept-suppression: thread = (col, part)
            {
                int col = tid & (CH_SZ - 1);
                int part = tid >> 7;               // 0..7, uniform per wave
                if (col < CH) {
                    float bx1 = cbox[col][0], by1 = cbox[col][1];
                    float bx2 = cbox[col][2], by2 = cbox[col][3], ba = cbox[col][4];
                    unsigned part16 = 0u;
                    int rbase = part << 4;
                    for (int k = 0; k < 16; ++k) {
                        int i2 = rbase + k;
                        if (i2 >= col || i2 >= CH) break;
                        if (iou_gt_half(cbox[i2][0], cbox[i2][1], cbox[i2][2], cbox[i2][3],
                                        cbox[i2][4], bx1, by1, bx2, by2, ba))
                            part16 |= (1u << k);
                    }
                    if (part16)
                        atomicOr(&maskW[col][part >> 1], part16 << ((part & 1) << 4));
                    bool f = false;
                    for (int k2 = part; k2 < nk0; k2 += 8) {
                        if (iou_gt_half(kept[k2][0], kept[k2][1], kept[k2][2], kept[k2][3],
                                        kept[k2][4], bx1, by1, bx2, by2, ba)) f = true;
                    }
                    if (f) atomicOr(&sup0w[col >> 5], 1u << (col & 31));
                }
            }
            __syncthreads();

            // serial greedy scan (wave 0): lanes 0..3 hold kept-bitset words
            if (wv == 0) {
                unsigned keptw = 0u;
                int nkv = nk0, lk = 0;
                unsigned pre0 = (lane < 4 && CH > 0) ? maskW[0][lane] : 0u;
                unsigned pre1 = (lane < 4 && CH > 1) ? maskW[1][lane] : 0u;
                for (int j = 0; j < CH && nkv < MAXDET; ++j) {
                    unsigned colw = pre0;
                    pre0 = pre1;
                    pre1 = (lane < 4 && (j + 2) < CH) ? maskW[j + 2][lane] : 0u;
                    bool hit = (keptw & colw) != 0u;
                    bool sup = __any(hit);
                    if ((sup0w[j >> 5] >> (j & 31)) & 1u) sup = true;
                    if (!sup) {
                        if (lane == (j >> 5)) keptw |= 1u << (j & 31);
                        if (lane == 0) klist[lk] = j;
                        lk++; nkv++;
                    }
                }
                if (lane == 0) { s_localk = lk; s_nk = nkv; }
            }
            __syncthreads();

            // epilogue: record kept boxes + write output rows
            int lk = s_localk;
            for (int t2 = tid; t2 < lk; t2 += 1024) {
                int i = klist[t2];
                int oidx = nk0 + t2;
                kept[oidx][0] = cbox[i][0]; kept[oidx][1] = cbox[i][1];
                kept[oidx][2] = cbox[i][2]; kept[oidx][3] = cbox[i][3];
                kept[oidx][4] = cbox[i][4];
                unsigned long long kk = skeys[c0 + i];
                unsigned bits = (unsigned)(kk >> 32);
                unsigned flat = 0xFFFFFFFFu - (unsigned)kk;
                unsigned bi = flat / (unsigned)NCLS;
                unsigned cc = flat - bi * (unsigned)NCLS;
                const float* rp = pb + (size_t)bi * ROWF;
                float cx = rp[0], cy = rp[1], wd = rp[2], ht = rp[3];
                float hw = __fmul_rn(0.5f, wd), hh = __fmul_rn(0.5f, ht);
                float* orow = ob + (size_t)oidx * 6;
                orow[0] = __fsub_rn(cx, hw);
                orow[1] = __fsub_rn(cy, hh);
                orow[2] = __fadd_rn(cx, hw);
                orow[3] = __fadd_rn(cy, hh);
                orow[4] = __uint_as_float(bits);
                orow[5] = (float)cc;
            }
            __syncthreads();
        }
        p = gEnd;
    }
#undef GSV
}

// ---------------- launch --------------------------------------------------------------
extern "C" void kernel_launch(void* const* d_in, const int* in_sizes, int n_in,
                              void* d_out, int out_size, void* d_ws, size_t ws_size,
                              hipStream_t stream) {
    const float* pred = (const float*)d_in[0];
    float* outp = (float*)d_out;
    char* ws = (char*)d_ws;

    // zeroed region first (contiguous)
    const size_t OFF_HIST = 0;
    const size_t SZ_HIST  = (size_t)BATCH * NBIN * 4;                // 196,608
    const size_t OFF_CUR  = OFF_HIST + SZ_HIST;
    const size_t SZ_CUR   = (size_t)BATCH * NBIN * 4;                // 196,608
    const size_t OFF_CCNT = OFF_CUR + SZ_CUR;
    const size_t SZ_CCNT  = (size_t)BATCH * 4;
    const size_t OFF_OFLW = OFF_CCNT + SZ_CCNT;
    const size_t SZ_OFLW  = (size_t)BATCH * 4;
    const size_t OFF_META = OFF_OFLW + SZ_OFLW;
    const size_t SZ_META  = (size_t)BATCH * 4 * 4;
    const size_t ZERO_SZ  = OFF_META + SZ_META;
    // non-zeroed
    const size_t OFF_SUF  = ZERO_SZ;
    const size_t SZ_SUF   = (size_t)BATCH * (NBIN + 1) * 4;          // 196,672
    const size_t OFF_SUF2 = OFF_SUF + SZ_SUF;
    const size_t SZ_SUF2  = (size_t)BATCH * (NBUCK + 1) * 4;         // 65,600
    const size_t OFF_KEYS = OFF_SUF2 + SZ_SUF2;
    const size_t SZ_KEYS  = (size_t)BATCH * CAP * 8;                 // 4,194,304
    const size_t OFF_GH   = OFF_KEYS + SZ_KEYS;
    const size_t SZ_GH    = (size_t)BATCH * SBLK2 * NBUCK * 4;       // 6,488,064
    const size_t OFF_CAND = OFF_GH + SZ_GH;
    const size_t SZ_CAND  = (size_t)BATCH * CANDCAP * 8;             // 16,777,216
    const size_t WS_NEEDED = OFF_CAND + SZ_CAND;                     // ~28.1 MB

    int staged = (ws_size >= WS_NEEDED) ? 1 : 0;

    unsigned* hist             = (unsigned*)(ws + OFF_HIST);
    unsigned* cursor           = (unsigned*)(ws + OFF_CUR);
    unsigned* ccnt             = (unsigned*)(ws + OFF_CCNT);
    unsigned* oflow            = (unsigned*)(ws + OFF_OFLW);
    int* meta                  = (int*)(ws + OFF_META);
    unsigned* suf              = (unsigned*)(ws + OFF_SUF);
    unsigned* suf2             = (unsigned*)(ws + OFF_SUF2);
    unsigned long long* keys   = (unsigned long long*)(ws + OFF_KEYS);
    unsigned* ghist            = (unsigned*)(ws + OFF_GH);
    unsigned long long* cand   = (unsigned long long*)(ws + OFF_CAND);

    hipMemsetAsync(ws, 0, ZERO_SZ, stream);
    hipMemsetAsync(d_out, 0, (size_t)out_size * sizeof(float), stream);

    k_stage<<<dim3(BATCH * SBLK2), dim3(256), 0, stream>>>(pred, ghist, ccnt, cand, oflow, staged);
    k_prep<<<dim3(BATCH), dim3(256), 0, stream>>>(ghist, ccnt, oflow, suf2, meta, staged);
    k_hist_fb<<<dim3(BATCH * SBLK), dim3(256), 0, stream>>>(pred, hist, meta);
    k_scan_fb<<<dim3(BATCH), dim3(256), 0, stream>>>(hist, suf, meta);
    k_scatter_fb<<<dim3(BATCH * SBLK), dim3(256), 0, stream>>>(pred, suf, meta, cursor, keys);
    k_nms<<<dim3(BATCH), dim3(1024), 0, stream>>>(pred, suf, suf2, meta, ccnt, keys, cand, outp);
}

// Round 6
// 347.701 us; speedup vs baseline: 1.0791x; 1.0791x over previous
//
#include <hip/hip_runtime.h>
#include <stdint.h>

#define BATCH 16
#define NROW 25200
#define NCLS 80
#define ROWF 85
#define MAXDET 300
#define MAXNMS 30000u
#define NBIN 3072
#define BASEBITS 0x3EC00000u
#define CAP 32768u
#define BATCH_FLOATS 2142000   // 25200*85

#define PREBIN 2048            // score >= 0.75
#define NBUCK 1024             // NBIN - PREBIN
#define CANDCAP 131072u
#define KMAX 2048u
#define TOPK 2048u             // target size of the pre-ordered head
#define K2CAP 4096u            // TOPK + max bin (1024) + slack

#define SORTCAP 1024
#define CH_SZ 128

// fallback-hist tiling
#define TILE_ROWS 80
#define TILE_FLOATS 6800
#define RPB 400
#define SUBT 5
#define SBLK 63

// staging grid
#define ROWS_PER_BLK 256
#define SBLK2 99               // ceil(25200/256)

// exact: fl(inter/den) > 0.5, division only at the rounding boundary
__device__ __forceinline__ bool iou_gt_half(float ax1, float ay1, float ax2, float ay2, float aa,
                                            float bx1, float by1, float bx2, float by2, float ba) {
    float ltx = fmaxf(ax1, bx1), lty = fmaxf(ay1, by1);
    float rbx = fminf(ax2, bx2), rby = fminf(ay2, by2);
    float wx = fmaxf(__fsub_rn(rbx, ltx), 0.0f);
    float wy = fmaxf(__fsub_rn(rby, lty), 0.0f);
    float inter = __fmul_rn(wx, wy);
    float den = __fadd_rn(__fsub_rn(__fadd_rn(aa, ba), inter), 1e-9f);
    float t = __fmul_rn(0.5f, den);
    if (!(inter > t)) return false;
    float tg = __fmul_rn(0.50000012f, den);
    if (inter >= tg) return true;
    return __fdiv_rn(inter, den) > 0.5f;
}

__device__ __forceinline__ unsigned bin_of_bits(unsigned bits) {
    unsigned v = (bits - BASEBITS) >> 12;
    if (v > (unsigned)(NBIN - 1)) v = NBIN - 1;
    return v;
}

// ---------------- K1: LDS-staged threshold filter -> dense array + global hist -------
__global__ __launch_bounds__(256) void k_stage(const float* __restrict__ pred,
                                               unsigned* __restrict__ hist2,
                                               unsigned* __restrict__ ccnt,
                                               unsigned long long* __restrict__ cand,
                                               unsigned* __restrict__ oflow,
                                               int staged) {
    if (!staged) return;
    __shared__ unsigned shist[NBUCK];
    __shared__ unsigned long long skey[KMAX];
    __shared__ unsigned s_cnt, s_n, s_base;
    int bx = blockIdx.x;
    int b = bx / SBLK2, blk = bx - b * SBLK2;
    int t = threadIdx.x, lane = t & 63, wv = t >> 6;
    for (int i = t; i < NBUCK; i += 256) shist[i] = 0u;
    if (t == 0) s_cnt = 0u;
    __syncthreads();
    const float* pb = pred + (size_t)b * BATCH_FLOATS;
    int r0 = blk * ROWS_PER_BLK + wv * 64;
    int rown = NROW - r0;
    if (rown > 0) {
        if (rown > 64) rown = 64;
        float obj = 0.0f;
        if (lane < rown) obj = pb[(size_t)(r0 + lane) * ROWF + 4];
        unsigned long long live = __ballot(obj > 0.4f);
        while (live) {
            int j = (int)__builtin_ctzll(live);
            live &= live - 1ULL;
            float o = __shfl(obj, j);
            const float* rp = pb + (size_t)(r0 + j) * ROWF;
            unsigned grow = (unsigned)(r0 + j);
            {
                float s = __fmul_rn(rp[5 + lane], o);   // exact numpy op order
                if (s >= 0.75f) {
                    unsigned bits = __float_as_uint(s);
                    unsigned bin = bin_of_bits(bits);
                    atomicAdd(&shist[bin - PREBIN], 1u);
                    unsigned u = atomicAdd(&s_cnt, 1u);
                    unsigned flat = grow * (unsigned)NCLS + (unsigned)lane;
                    if (u < KMAX)
                        skey[u] = ((unsigned long long)bits << 32) |
                                  (unsigned long long)(0xFFFFFFFFu - flat);
                    else oflow[b] = 1u;
                }
            }
            if (lane < 16) {
                int c = 64 + lane;
                float s = __fmul_rn(rp[5 + c], o);
                if (s >= 0.75f) {
                    unsigned bits = __float_as_uint(s);
                    unsigned bin = bin_of_bits(bits);
                    atomicAdd(&shist[bin - PREBIN], 1u);
                    unsigned u = atomicAdd(&s_cnt, 1u);
                    unsigned flat = grow * (unsigned)NCLS + (unsigned)c;
                    if (u < KMAX)
                        skey[u] = ((unsigned long long)bits << 32) |
                                  (unsigned long long)(0xFFFFFFFFu - flat);
                    else oflow[b] = 1u;
                }
            }
        }
    }
    __syncthreads();
    unsigned* gh = hist2 + (size_t)b * NBUCK;
    for (int i = t; i < NBUCK; i += 256) {
        unsigned v = shist[i];
        if (v) atomicAdd(&gh[i], v);   // ~500 atomics/block over 16k cells: low contention
    }
    if (t == 0) {
        unsigned n = s_cnt;
        if (n > KMAX) n = KMAX;
        unsigned base = atomicAdd(&ccnt[b], n);
        if (base + n > CANDCAP) oflow[b] = 1u;
        s_n = n; s_base = base;
    }
    __syncthreads();
    unsigned n = s_n, base = s_base;
    if (base + n <= CANDCAP) {
        unsigned long long* cd = cand + (size_t)b * CANDCAP + base;
        for (unsigned k = t; k < n; k += 256) cd[k] = skey[k];
    }
}

// ---------------- K2: scan hist -> meta + suf2, scatter top-TOPK into keys2 ----------
__global__ __launch_bounds__(1024) void k_prep(const unsigned* __restrict__ hist2,
                                               const unsigned* __restrict__ ccnt,
                                               const unsigned* __restrict__ oflow,
                                               const unsigned long long* __restrict__ cand,
                                               unsigned* __restrict__ suf2,
                                               unsigned long long* __restrict__ keys2,
                                               int* __restrict__ meta,
                                               int staged) {
    __shared__ unsigned sS[NBUCK];
    __shared__ unsigned scur[NBUCK];
    __shared__ int s_cut, s_need, s_tot, s_T, s_valid;
    __shared__ unsigned s_bad, s_E;
    int b = blockIdx.x, t = threadIdx.x;   // 1024 threads == NBUCK
    unsigned h = hist2[(size_t)b * NBUCK + t];
    sS[t] = h;
    if (t == 0) { s_cut = -1; s_T = -1; s_bad = 0u; s_need = 0; s_tot = 0; s_E = 0u; }
    __syncthreads();
    if (h > (unsigned)SORTCAP) atomicOr(&s_bad, 1u);
    for (int off = 1; off < NBUCK; off <<= 1) {
        unsigned v = (t + off < NBUCK) ? sS[t + off] : 0u;
        __syncthreads();
        sS[t] += v;
        __syncthreads();
    }
    unsigned Sv = sS[t];
    unsigned Sn = (t + 1 < NBUCK) ? sS[t + 1] : 0u;
    if (Sv >= MAXNMS && Sn < MAXNMS) {
        s_cut = PREBIN + t; s_need = (int)(MAXNMS - Sn); s_tot = (int)Sv;
    }
    if (Sv >= TOPK && Sn < TOPK) { s_T = PREBIN + t; s_E = Sv; }
    unsigned* g2 = suf2 + (size_t)b * (NBUCK + 1);
    g2[t] = Sv;
    if (t == 0) g2[NBUCK] = 0u;
    scur[t] = Sn;                      // scatter base for bin PREBIN+t = S(v+1)
    __syncthreads();
    if (t == 0) {
        int valid = (staged && s_cut >= 0 && s_T >= 0 && s_bad == 0u &&
                     oflow[b] == 0u && ccnt[b] <= CANDCAP) ? 1 : 0;
        s_valid = valid;
        meta[b * 8 + 0] = valid ? s_cut : 0;
        meta[b * 8 + 1] = valid ? s_need : 0;
        meta[b * 8 + 2] = valid ? s_tot : 0;
        meta[b * 8 + 3] = valid;
        meta[b * 8 + 4] = valid ? s_T : 0;
        meta[b * 8 + 5] = valid ? (int)s_E : 0;
    }
    __syncthreads();
    if (s_valid) {
        int T = s_T;
        unsigned ccb = ccnt[b];
        const unsigned long long* cd = cand + (size_t)b * CANDCAP;
        unsigned long long* k2 = keys2 + (size_t)b * K2CAP;
        for (unsigned k = t; k < ccb; k += 1024) {
            unsigned long long key = cd[k];
            unsigned v = bin_of_bits((unsigned)(key >> 32));
            if ((int)v >= T) {
                unsigned pos = atomicAdd(&scur[v - PREBIN], 1u);
                if (pos < K2CAP) k2[pos] = key;
            }
        }
    }
}

// ---------------- K3a (fallback): full histogram ------------------------------------
__global__ __launch_bounds__(256) void k_hist_fb(const float* __restrict__ pred,
                                                 unsigned* __restrict__ hist,
                                                 const int* __restrict__ meta) {
    int bx = blockIdx.x;
    int b = bx / SBLK, blk = bx - b * SBLK;
    if (meta[b * 8 + 3]) return;
    __shared__ __align__(16) float rows[TILE_FLOATS];
    __shared__ unsigned shist[NBIN];
    int t = threadIdx.x, lane = t & 63, wv = t >> 6;
    for (int i = t; i < NBIN; i += 256) shist[i] = 0u;
    const float* pbase = pred + (size_t)b * BATCH_FLOATS + (size_t)blk * RPB * ROWF;
    for (int st = 0; st < SUBT; ++st) {
        __syncthreads();
        const float4* src = (const float4*)(pbase + (size_t)st * TILE_ROWS * ROWF);
        float4* dst = (float4*)rows;
        for (int i = t; i < TILE_FLOATS / 4; i += 256) dst[i] = src[i];
        __syncthreads();
        for (int r = wv; r < TILE_ROWS; r += 4) {
            float obj = rows[r * ROWF + 4];
            if (!(obj > 0.4f)) continue;
            for (int half = 0; half < 2; ++half) {
                int c = lane + (half << 6);
                if (c < NCLS) {
                    float s = __fmul_rn(rows[r * ROWF + 5 + c], obj);
                    if (s > 0.4f) atomicAdd(&shist[bin_of_bits(__float_as_uint(s))], 1u);
                }
            }
        }
    }
    __syncthreads();
    unsigned* gh = hist + (size_t)b * NBIN;
    for (int i = t; i < NBIN; i += 256) {
        unsigned v = shist[i];
        if (v) atomicAdd(&gh[i], v);
    }
}

// ---------------- K3b (fallback): suffix-scan full hist -> meta + suf ----------------
__global__ __launch_bounds__(256) void k_scan_fb(const unsigned* __restrict__ hist,
                                                 unsigned* __restrict__ suf,
                                                 int* __restrict__ meta) {
    int b = blockIdx.x, t = threadIdx.x;
    if (meta[b * 8 + 3]) return;
    __shared__ unsigned sh[NBIN];
    __shared__ unsigned sS[NBIN];
    __shared__ unsigned cs[256];
    __shared__ int s_cut, s_need, s_tot;
    const unsigned* gh = hist + (size_t)b * NBIN;
    for (int i = t; i < NBIN; i += 256) sh[i] = gh[i];
    if (t == 0) { s_cut = 0; s_need = 0x7FFFFFFF; s_tot = 0; }
    __syncthreads();
    const int CHUNK = NBIN / 256;
    int base = t * CHUNK;
    unsigned tot = 0;
    for (int i = 0; i < CHUNK; ++i) tot += sh[base + i];
    cs[t] = tot;
    __syncthreads();
    for (int off = 1; off < 256; off <<= 1) {
        unsigned v = (t + off < 256) ? cs[t + off] : 0u;
        __syncthreads();
        cs[t] += v;
        __syncthreads();
    }
    unsigned after = (t + 1 < 256) ? cs[t + 1] : 0u;
    for (int i = CHUNK - 1; i >= 0; --i) {
        after += sh[base + i];
        sS[base + i] = after;
    }
    __syncthreads();
    unsigned* gs = suf + (size_t)b * (NBIN + 1);
    for (int i = t; i < NBIN; i += 256) gs[i] = sS[i];
    if (t == 0) gs[NBIN] = 0u;
    for (int i = 0; i < CHUNK; ++i) {
        int v = base + i;
        unsigned Sv = sS[v];
        unsigned Sn = (v + 1 < NBIN) ? sS[v + 1] : 0u;
        if (Sv >= MAXNMS && Sn < MAXNMS) {
            s_cut = v; s_need = (int)(MAXNMS - Sn); s_tot = (int)Sv;
        }
    }
    __syncthreads();
    if (t == 0) {
        int cut = s_cut, needv = s_need, totv = s_tot;
        if (sS[0] < MAXNMS) { cut = 0; needv = 0x7FFFFFFF; totv = (int)sS[0]; }
        meta[b * 8 + 0] = cut;
        meta[b * 8 + 1] = needv;
        meta[b * 8 + 2] = totv;
    }
}

// ---------------- K3c (fallback): full re-read counting-scatter ----------------------
__global__ __launch_bounds__(256) void k_scatter_fb(const float* __restrict__ pred,
                                                    const unsigned* __restrict__ suf,
                                                    const int* __restrict__ meta,
                                                    unsigned* __restrict__ cursor,
                                                    unsigned long long* __restrict__ keys) {
    int bx = blockIdx.x;
    int b = bx / SBLK, blk = bx - b * SBLK;
    if (meta[b * 8 + 3]) return;
    __shared__ __align__(16) float rows[TILE_FLOATS];
    int t = threadIdx.x, lane = t & 63, wv = t >> 6;
    int cutbin = meta[b * 8 + 0];
    const float* pbase = pred + (size_t)b * BATCH_FLOATS + (size_t)blk * RPB * ROWF;
    unsigned rowbase0 = (unsigned)(blk * RPB);
    const unsigned* gs = suf + (size_t)b * (NBIN + 1);
    unsigned* cur = cursor + (size_t)b * NBIN;
    unsigned long long* kb = keys + (size_t)b * CAP;
    for (int st = 0; st < SUBT; ++st) {
        __syncthreads();
        const float4* src = (const float4*)(pbase + (size_t)st * TILE_ROWS * ROWF);
        float4* dst = (float4*)rows;
        for (int i = t; i < TILE_FLOATS / 4; i += 256) dst[i] = src[i];
        __syncthreads();
        for (int r = wv; r < TILE_ROWS; r += 4) {
            float obj = rows[r * ROWF + 4];
            if (!(obj > 0.4f)) continue;
            unsigned grow = rowbase0 + (unsigned)(st * TILE_ROWS + r);
            for (int half = 0; half < 2; ++half) {
                int c = lane + (half << 6);
                if (c < NCLS) {
                    float s = __fmul_rn(rows[r * ROWF + 5 + c], obj);
                    if (s > 0.4f) {
                        unsigned bits = __float_as_uint(s);
                        unsigned bin = bin_of_bits(bits);
                        if ((int)bin >= cutbin) {
                            unsigned pos = gs[bin + 1] + atomicAdd(&cur[bin], 1u);
                            if (pos < CAP) {
                                unsigned flat = grow * (unsigned)NCLS + (unsigned)c;
                                kb[pos] = ((unsigned long long)bits << 32) |
                                          (unsigned long long)(0xFFFFFFFFu - flat);
                            }
                        }
                    }
                }
            }
        }
    }
}

// ---------------- K4: NMS — contiguous keys2 gather, in-bin rank, 128-chunk mask -----
__global__ __launch_bounds__(1024) void k_nms(const float* __restrict__ pred,
                                              const unsigned* __restrict__ suf,
                                              const unsigned* __restrict__ suf2,
                                              const int* __restrict__ meta,
                                              const unsigned* __restrict__ ccnt,
                                              const unsigned long long* __restrict__ keys,
                                              const unsigned long long* __restrict__ keys2,
                                              const unsigned long long* __restrict__ cand,
                                              float* __restrict__ out) {
    __shared__ unsigned sgsL[NBUCK + 1];
    __shared__ unsigned long long ktmp[SORTCAP];
    __shared__ unsigned long long skeys[SORTCAP];
    __shared__ unsigned maskW[CH_SZ][5];
    __shared__ unsigned sup0w[4];
    __shared__ float cbox[CH_SZ][9];
    __shared__ float kept[MAXDET][5];
    __shared__ int klist[MAXDET];
    __shared__ int s_nk, s_localk;
    __shared__ unsigned s_gc;

    int b = blockIdx.x;
    int tid = threadIdx.x;
    int lane = tid & 63, wv = tid >> 6;

    int cutbin = meta[b * 8 + 0];
    int needv  = meta[b * 8 + 1];
    unsigned total = (unsigned)meta[b * 8 + 2];
    int valid  = meta[b * 8 + 3];
    int Tbin   = meta[b * 8 + 4];
    unsigned E = valid ? (unsigned)meta[b * 8 + 5] : 0u;
    if (!valid && total > CAP) total = CAP;
    const unsigned* gs = suf + (size_t)b * (NBIN + 1);
    const unsigned* g2 = suf2 + (size_t)b * (NBUCK + 1);
    const unsigned long long* kb = keys + (size_t)b * CAP;
    const unsigned long long* k2 = keys2 + (size_t)b * K2CAP;
    const unsigned long long* cd = cand + (size_t)b * CANDCAP;
    unsigned ccb = valid ? ccnt[b] : 0u;
    if (ccb > CANDCAP) ccb = CANDCAP;
    const float* pb = pred + (size_t)b * BATCH_FLOATS;
    float* ob = out + (size_t)b * MAXDET * 6;

    if (valid) for (int i = tid; i < NBUCK + 1; i += 1024) sgsL[i] = g2[i];
    if (tid == 0) s_nk = 0;
    __syncthreads();

#define GSV(v) (valid ? sgsL[(v) - PREBIN] : gs[(v)])

    unsigned limit;
    if (needv == 0x7FFFFFFF) limit = total;
    else limit = GSV(cutbin + 1) + (unsigned)needv;
    if (limit > total) limit = total;

    unsigned p = 0;
    while (p < limit) {
        if (s_nk >= MAXDET) break;

        // vs = smallest v with GSV(v) <= p + SORTCAP  -> maximal whole-bin extent
        int lo = cutbin, hi = NBIN - 1, vs = NBIN - 1;
        while (lo <= hi) { int mid = (lo + hi) >> 1;
            if (GSV(mid) <= p + (unsigned)SORTCAP) { vs = mid; hi = mid - 1; } else lo = mid + 1; }
        unsigned gEnd = GSV(vs);
        bool phaseA = (!valid) || (p < E);
        if (valid && phaseA && gEnd > E) gEnd = E;
        if (gEnd > total) gEnd = total;
        if (gEnd <= p) { gEnd = p + (unsigned)SORTCAP; if (gEnd > total) gEnd = total; }  // defensive
        unsigned G = gEnd - p;

        if (phaseA) {
            // dense bin-partitioned source indexed by absolute rank
            const unsigned long long* src = valid ? k2 : kb;
            unsigned myLo = 0, myHi = 0;
            unsigned long long raw = 0ULL;
            if (tid < (int)G) {
                unsigned idx = p + (unsigned)tid;
                int l2 = cutbin, h2 = NBIN - 1, v = cutbin;
                while (l2 <= h2) { int mid = (l2 + h2) >> 1;
                    if (GSV(mid) > idx) { v = mid; l2 = mid + 1; } else h2 = mid - 1; }
                unsigned bstart = GSV(v + 1);
                unsigned bend = GSV(v);
                raw = src[idx];
                myLo = (bstart > p) ? (bstart - p) : 0u;
                myHi = bend - p; if (myHi > G) myHi = G;
                ktmp[tid] = raw;
            }
            __syncthreads();
            if (tid < (int)G) {
                unsigned rank = 0;
                for (unsigned u = myLo; u < myHi; ++u) rank += (ktmp[u] > raw) ? 1u : 0u;
                skeys[myLo + rank] = raw;
            }
            __syncthreads();
        } else {
            // phase B (rare): filter-scan dense array for bins [vs, w1]
            int l0 = cutbin, h0 = NBIN - 1, w1 = cutbin;
            while (l0 <= h0) { int mid = (l0 + h0) >> 1;
                if (GSV(mid) > p) { w1 = mid; l0 = mid + 1; } else h0 = mid - 1; }
            if (tid == 0) s_gc = 0u;
            __syncthreads();
            for (unsigned k = tid; k < ccb; k += 1024) {
                unsigned long long key = cd[k];
                unsigned v = bin_of_bits((unsigned)(key >> 32));
                if ((int)v >= vs && (int)v <= w1) {
                    unsigned u = atomicAdd(&s_gc, 1u);
                    if (u < (unsigned)SORTCAP) ktmp[u] = key;
                }
            }
            __syncthreads();
            unsigned Gc = s_gc; if (Gc > (unsigned)SORTCAP) Gc = (unsigned)SORTCAP;
            if (tid < (int)Gc) {
                unsigned long long key = ktmp[tid];
                unsigned v = bin_of_bits((unsigned)(key >> 32));
                unsigned bstart = GSV(v + 1);
                unsigned rank = 0;
                for (unsigned u = 0; u < Gc; ++u) {
                    unsigned long long kk = ktmp[u];
                    unsigned vu = bin_of_bits((unsigned)(kk >> 32));
                    rank += (vu == v && kk > key) ? 1u : 0u;
                }
                skeys[(bstart - p) + rank] = key;
            }
            __syncthreads();
        }

        unsigned consumable = limit - p; if (consumable > G) consumable = G;

        for (unsigned c0 = 0; c0 < consumable; c0 += CH_SZ) {
            int nk0 = s_nk;
            if (nk0 >= MAXDET) break;
            int CH = (int)((consumable - c0 < (unsigned)CH_SZ) ? (consumable - c0) : (unsigned)CH_SZ);

            if (tid < CH_SZ * 5) maskW[tid / 5][tid % 5] = 0u;
            if (tid >= CH_SZ * 5 && tid < CH_SZ * 5 + 4) sup0w[tid - CH_SZ * 5] = 0u;
            if (tid < CH) {
                unsigned long long kk = skeys[c0 + tid];
                unsigned flat = 0xFFFFFFFFu - (unsigned)kk;
                unsigned bi = flat / (unsigned)NCLS;
                unsigned cc = flat - bi * (unsigned)NCLS;
                const float* rp = pb + (size_t)bi * ROWF;
                float cx = rp[0], cy = rp[1], wd = rp[2], ht = rp[3];
                float hw = __fmul_rn(0.5f, wd), hh = __fmul_rn(0.5f, ht);
                float off = __fmul_rn((float)cc, 4096.0f);
                float x1 = __fsub_rn(cx, hw), y1 = __fsub_rn(cy, hh);
                float x2 = __fadd_rn(cx, hw), y2 = __fadd_rn(cy, hh);
                float ox1 = __fadd_rn(x1, off), oy1 = __fadd_rn(y1, off);
                float ox2 = __fadd_rn(x2, off), oy2 = __fadd_rn(y2, off);
                cbox[tid][0] = ox1; cbox[tid][1] = oy1;
                cbox[tid][2] = ox2; cbox[tid][3] = oy2;
                cbox[tid][4] = __fmul_rn(__fsub_rn(ox2, ox1), __fsub_rn(oy2, oy1));
            }
            __syncthreads();

            {
                int col = tid & (CH_SZ - 1);
                int part = tid >> 7;
                if (col < CH) {
                    float bx1 = cbox[col][0], by1 = cbox[col][1];
                    float bx2 = cbox[col][2], by2 = cbox[col][3], ba = cbox[col][4];
                    unsigned part16 = 0u;
                    int rbase = part << 4;
                    for (int k = 0; k < 16; ++k) {
                        int i2 = rbase + k;
                        if (i2 >= col || i2 >= CH) break;
                        if (iou_gt_half(cbox[i2][0], cbox[i2][1], cbox[i2][2], cbox[i2][3],
                                        cbox[i2][4], bx1, by1, bx2, by2, ba))
                            part16 |= (1u << k);
                    }
                    if (part16)
                        atomicOr(&maskW[col][part >> 1], part16 << ((part & 1) << 4));
                    bool f = false;
                    for (int k2 = part; k2 < nk0; k2 += 8) {
                        if (iou_gt_half(kept[k2][0], kept[k2][1], kept[k2][2], kept[k2][3],
                                        kept[k2][4], bx1, by1, bx2, by2, ba)) f = true;
                    }
                    if (f) atomicOr(&sup0w[col >> 5], 1u << (col & 31));
                }
            }
            __syncthreads();

            if (wv == 0) {
                unsigned keptw = 0u;
                int nkv = nk0, lk = 0;
                unsigned pre0 = (lane < 4 && CH > 0) ? maskW[0][lane] : 0u;
                unsigned pre1 = (lane < 4 && CH > 1) ? maskW[1][lane] : 0u;
                for (int j = 0; j < CH && nkv < MAXDET; ++j) {
                    unsigned colw = pre0;
                    pre0 = pre1;
                    pre1 = (lane < 4 && (j + 2) < CH) ? maskW[j + 2][lane] : 0u;
                    bool hit = (keptw & colw) != 0u;
                    bool sup = __any(hit);
                    if ((sup0w[j >> 5] >> (j & 31)) & 1u) sup = true;
                    if (!sup) {
                        if (lane == (j >> 5)) keptw |= 1u << (j & 31);
                        if (lane == 0) klist[lk] = j;
                        lk++; nkv++;
                    }
                }
                if (lane == 0) { s_localk = lk; s_nk = nkv; }
            }
            __syncthreads();

            int lk = s_localk;
            for (int t2 = tid; t2 < lk; t2 += 1024) {
                int i = klist[t2];
                int oidx = nk0 + t2;
                kept[oidx][0] = cbox[i][0]; kept[oidx][1] = cbox[i][1];
                kept[oidx][2] = cbox[i][2]; kept[oidx][3] = cbox[i][3];
                kept[oidx][4] = cbox[i][4];
                unsigned long long kk = skeys[c0 + i];
                unsigned bits = (unsigned)(kk >> 32);
                unsigned flat = 0xFFFFFFFFu - (unsigned)kk;
                unsigned bi = flat / (unsigned)NCLS;
                unsigned cc = flat - bi * (unsigned)NCLS;
                const float* rp = pb + (size_t)bi * ROWF;
                float cx = rp[0], cy = rp[1], wd = rp[2], ht = rp[3];
                float hw = __fmul_rn(0.5f, wd), hh = __fmul_rn(0.5f, ht);
                float* orow = ob + (size_t)oidx * 6;
                orow[0] = __fsub_rn(cx, hw);
                orow[1] = __fsub_rn(cy, hh);
                orow[2] = __fadd_rn(cx, hw);
                orow[3] = __fadd_rn(cy, hh);
                orow[4] = __uint_as_float(bits);
                orow[5] = (float)cc;
            }
            __syncthreads();
        }
        p = gEnd;
    }
#undef GSV
}

// ---------------- launch --------------------------------------------------------------
extern "C" void kernel_launch(void* const* d_in, const int* in_sizes, int n_in,
                              void* d_out, int out_size, void* d_ws, size_t ws_size,
                              hipStream_t stream) {
    const float* pred = (const float*)d_in[0];
    float* outp = (float*)d_out;
    char* ws = (char*)d_ws;

    // zeroed region (contiguous)
    const size_t OFF_HIST  = 0;
    const size_t SZ_HIST   = (size_t)BATCH * NBIN * 4;               // 196,608
    const size_t OFF_CUR   = OFF_HIST + SZ_HIST;
    const size_t SZ_CUR    = (size_t)BATCH * NBIN * 4;               // 196,608
    const size_t OFF_H2    = OFF_CUR + SZ_CUR;
    const size_t SZ_H2     = (size_t)BATCH * NBUCK * 4;              // 65,536
    const size_t OFF_CCNT  = OFF_H2 + SZ_H2;
    const size_t SZ_CCNT   = (size_t)BATCH * 4;
    const size_t OFF_OFLW  = OFF_CCNT + SZ_CCNT;
    const size_t SZ_OFLW   = (size_t)BATCH * 4;
    const size_t OFF_META  = OFF_OFLW + SZ_OFLW;
    const size_t SZ_META   = (size_t)BATCH * 8 * 4;
    const size_t ZERO_SZ   = OFF_META + SZ_META;
    // non-zeroed
    const size_t OFF_SUF   = ZERO_SZ;
    const size_t SZ_SUF    = (size_t)BATCH * (NBIN + 1) * 4;
    const size_t OFF_SUF2  = OFF_SUF + SZ_SUF;
    const size_t SZ_SUF2   = (size_t)BATCH * (NBUCK + 1) * 4;
    const size_t OFF_KEYS  = OFF_SUF2 + SZ_SUF2;
    const size_t SZ_KEYS   = (size_t)BATCH * CAP * 8;                // 4,194,304
    const size_t OFF_K2    = OFF_KEYS + SZ_KEYS;
    const size_t SZ_K2     = (size_t)BATCH * K2CAP * 8;              // 524,288
    const size_t OFF_CAND  = OFF_K2 + SZ_K2;
    const size_t SZ_CAND   = (size_t)BATCH * CANDCAP * 8;            // 16,777,216
    const size_t WS_NEEDED = OFF_CAND + SZ_CAND;                     // ~22.4 MB

    int staged = (ws_size >= WS_NEEDED) ? 1 : 0;

    unsigned* hist             = (unsigned*)(ws + OFF_HIST);
    unsigned* cursor           = (unsigned*)(ws + OFF_CUR);
    unsigned* hist2            = (unsigned*)(ws + OFF_H2);
    unsigned* ccnt             = (unsigned*)(ws + OFF_CCNT);
    unsigned* oflow            = (unsigned*)(ws + OFF_OFLW);
    int* meta                  = (int*)(ws + OFF_META);
    unsigned* suf              = (unsigned*)(ws + OFF_SUF);
    unsigned* suf2             = (unsigned*)(ws + OFF_SUF2);
    unsigned long long* keys   = (unsigned long long*)(ws + OFF_KEYS);
    unsigned long long* keys2  = (unsigned long long*)(ws + OFF_K2);
    unsigned long long* cand   = (unsigned long long*)(ws + OFF_CAND);

    hipMemsetAsync(ws, 0, ZERO_SZ, stream);
    hipMemsetAsync(d_out, 0, (size_t)out_size * sizeof(float), stream);

    k_stage<<<dim3(BATCH * SBLK2), dim3(256), 0, stream>>>(pred, hist2, ccnt, cand, oflow, staged);
    k_prep<<<dim3(BATCH), dim3(1024), 0, stream>>>(hist2, ccnt, oflow, cand, suf2, keys2, meta, staged);
    k_hist_fb<<<dim3(BATCH * SBLK), dim3(256), 0, stream>>>(pred, hist, meta);
    k_scan_fb<<<dim3(BATCH), dim3(256), 0, stream>>>(hist, suf, meta);
    k_scatter_fb<<<dim3(BATCH * SBLK), dim3(256), 0, stream>>>(pred, suf, meta, cursor, keys);
    k_nms<<<dim3(BATCH), dim3(1024), 0, stream>>>(pred, suf, suf2, meta, ccnt, keys, keys2, cand, outp);
}